// Round 4
// baseline (276.044 us; speedup 1.0000x reference)
//
#include <hip/hip_runtime.h>

#define T   512
#define B   512
#define NT  64
#define NC  8             // chunks per sequence
#define CS  64            // steps per chunk
#define QS  16            // (fallback kernel) steps per staging quarter
#define NQ  (T / QS)
#define RING 4

typedef _Float16 h2 __attribute__((ext_vector_type(2)));
typedef _Float16 h8 __attribute__((ext_vector_type(8)));
typedef float   f16x __attribute__((ext_vector_type(16)));
typedef unsigned int uint;

__device__ __forceinline__ float rflf(float x) {
    return __uint_as_float(__builtin_amdgcn_readfirstlane(__float_as_uint(x)));
}

__device__ __forceinline__ float dot2(h2 a, h2 b, float c) {
#if __has_builtin(__builtin_amdgcn_fdot2)
    return __builtin_amdgcn_fdot2(a, b, c, false);
#else
    return c + (float)a.x * (float)b.x + (float)a.y * (float)b.y;
#endif
}

__device__ __forceinline__ h2 bch2(int u) { return __builtin_bit_cast(h2, u); }

__device__ __forceinline__ int cvtpk(float a, float b) {
    return __builtin_bit_cast(int, __builtin_amdgcn_cvt_pkrtz(a, b));
}

// ===========================================================================
// Phase 1: per (batch, chunk) wave computes the 64x64 chunk transfer matrix
//   A_c = Prod_{t in chunk, mask[t]} ( diag(X_t) E^T ),  X_t = exp(emissions_t)
// by propagating S <- diag(X)E^T S with mfma_f32_32x32x16_f16.
//   A-op  = X-row-scaled E^T fragments (E^T const in regs, 32 h2),
//   B-op  = S fragments (32 h2), C = 2x2 tiles of 32x32 f32.
// Per-step power-of-2 renorm (lag-1, folded into next X-scale), scalar K_c.
// C/D->B conversion: cvt_pkrtz pairs + hi-half exchange via ds_bpermute.
// Output: A_c rows as f16-pairs (row-major words) + K_c, for phase 2.
// ===========================================================================
__global__ __launch_bounds__(64) void crf_chunks(
    const float* __restrict__ emissions,  // [T, B, NT]
    const int*   __restrict__ mask,       // [T, B]
    const float* __restrict__ trans,      // [NT, NT]
    uint* __restrict__ wsA,               // [B*NC][64][32] words
    int*  __restrict__ wsK)               // [B*NC]
{
    const int l   = threadIdx.x;
    const int bc  = blockIdx.x;           // b*NC + c
    const int b   = bc >> 3;
    const int c   = bc & 7;
    const int col = l & 31;
    const int hi  = l >> 5;

    __shared__ __align__(16) float xs[CS][NT];   // X rows, 16 KB

    // ---- stage X = exp(emissions) for this chunk ----
    const int t0 = c * CS;
    {
        const int rr = l >> 4;            // 0..3
        const int cc = (l & 15) * 4;
#pragma unroll
        for (int p = 0; p < 16; ++p) {
            const int tt = p * 4 + rr;
            float4 v = *(const float4*)&emissions[((size_t)(t0 + tt) * B + b) * NT + cc];
            float4 w;
            w.x = __expf(v.x); w.y = __expf(v.y);
            w.z = __expf(v.z); w.w = __expf(v.w);
            *(float4*)&xs[tt][cc] = w;
        }
    }
    const unsigned long long mbc = __ballot(mask[(t0 + l) * B + b] != 0);

    // ---- constant A fragments of E^T: Ac[to][ks][r] = (E[k][m], E[k+1][m]),
    //      k = ks*16 + 8*hi + 2r, m = to*32 + col ----
    h2 Ac[2][4][4];
#pragma unroll
    for (int to = 0; to < 2; ++to)
#pragma unroll
        for (int ks = 0; ks < 4; ++ks)
#pragma unroll
            for (int r = 0; r < 4; ++r) {
                const int k = ks * 16 + 8 * hi + 2 * r;
                const int m = to * 32 + col;
                h2 e;
                e.x = (_Float16)__expf(trans[k * NT + m]);
                e.y = (_Float16)__expf(trans[(k + 1) * NT + m]);
                Ac[to][ks][r] = e;
            }

    // ---- S = I as B fragments: Sb[ks][tj][r] = (S[k][n], S[k+1][n]),
    //      n = col + 32*tj ----
    h2 Sb[4][2][4];
#pragma unroll
    for (int ks = 0; ks < 4; ++ks)
#pragma unroll
        for (int tj = 0; tj < 2; ++tj)
#pragma unroll
            for (int r = 0; r < 4; ++r) {
                const int k = ks * 16 + 8 * hi + 2 * r;
                const int n = col + 32 * tj;
                h2 e;
                e.x = (k     == n) ? (_Float16)1.f : (_Float16)0.f;
                e.y = (k + 1 == n) ? (_Float16)1.f : (_Float16)0.f;
                Sb[ks][tj][r] = e;
            }

    __syncthreads();

    const int paddr = (l ^ 32) << 2;      // bpermute partner (lane^32)
    int Kc = 0;
    int kp = -6;                          // first applied scale = 2^{-(kp+6)} = 1
    const int sBeg = (c == 0) ? 1 : 0;    // t=0 belongs to the init vector

#pragma unroll 1
    for (int tt = sBeg; tt < CS; ++tt) {
        if (!((mbc >> tt) & 1ull)) continue;   // masked step: M = I

        // X scale (includes lag-1 renorm + 2^-6 f16 headroom bias)
        const float sc = __int_as_float((127 - kp - 6) << 23);
        Kc += kp + 6;
        const float x0 = xs[tt][col]      * sc;
        const float x1 = xs[tt][col + 32] * sc;
        const h2 X0 = bch2(cvtpk(x0, x0));
        const h2 X1 = bch2(cvtpk(x1, x1));

        f16x c00 = {}, c01 = {}, c10 = {}, c11 = {};
#pragma unroll
        for (int ks = 0; ks < 4; ++ks) {
            union { h2 p[4]; h8 v; } a0, a1, b0, b1;
#pragma unroll
            for (int r = 0; r < 4; ++r) {
                a0.p[r] = Ac[0][ks][r] * X0;   // v_pk_mul_f16 row-scale
                a1.p[r] = Ac[1][ks][r] * X1;
                b0.p[r] = Sb[ks][0][r];
                b1.p[r] = Sb[ks][1][r];
            }
            c00 = __builtin_amdgcn_mfma_f32_32x32x16_f16(a0.v, b0.v, c00, 0, 0, 0);
            c01 = __builtin_amdgcn_mfma_f32_32x32x16_f16(a0.v, b1.v, c01, 0, 0, 0);
            c10 = __builtin_amdgcn_mfma_f32_32x32x16_f16(a1.v, b0.v, c10, 0, 0, 0);
            c11 = __builtin_amdgcn_mfma_f32_32x32x16_f16(a1.v, b1.v, c11, 0, 0, 0);
        }

        // renorm exponent from one representative entry (applied next step)
        kp = ((__builtin_amdgcn_readfirstlane(__float_as_int(c00[0])) >> 23) & 255) - 127;

        // ---- convert C (f32, C/D layout) -> next S (f16, B layout) ----
        // acc reg r in [8h,8h+8): local rows {16h + (r&3)+8*(r>>2) + 4hi}.
        // B reg r' wants k = ks*16 + 8hi + 2r'; the missing half lives in
        // lane^32 at the same column -> one ds_bpermute per word pair.
        auto conv = [&](const f16x& A16, int to, int tj) {
#pragma unroll
            for (int h = 0; h < 2; ++h) {
                const int base = 8 * h;
                const int w0 = cvtpk(A16[base + 0], A16[base + 1]);
                const int w1 = cvtpk(A16[base + 2], A16[base + 3]);
                const int w2 = cvtpk(A16[base + 4], A16[base + 5]);
                const int w3 = cvtpk(A16[base + 6], A16[base + 7]);
                const int za  = hi ? w0 : w2;              // value to send
                const int zb  = hi ? w1 : w3;
                const int zza = __builtin_amdgcn_ds_bpermute(paddr, za);
                const int zzb = __builtin_amdgcn_ds_bpermute(paddr, zb);
                const int ks = 2 * to + h;
                Sb[ks][tj][0] = bch2(hi ? zza : w0);
                Sb[ks][tj][1] = bch2(hi ? zzb : w1);
                Sb[ks][tj][2] = bch2(hi ? w2 : zza);
                Sb[ks][tj][3] = bch2(hi ? w3 : zzb);
            }
        };
        conv(c00, 0, 0); conv(c01, 0, 1); conv(c10, 1, 0); conv(c11, 1, 1);
    }

    // ---- store A_c as row-major f16-pair words for phase 2 ----
    // Sb[ks][tj][r] = (S[k][n], S[k+1][n]); row-word (j, w) = (S[j][2w], S[j][2w+1])
    // built from neighbor column via DPP xor-1.
    const uint rowbase = (uint)(bc << 6);
#pragma unroll
    for (int ks = 0; ks < 4; ++ks)
#pragma unroll
        for (int tj = 0; tj < 2; ++tj)
#pragma unroll
            for (int r = 0; r < 4; ++r) {
                const int w  = __builtin_bit_cast(int, Sb[ks][tj][r]);
                const int nb = __builtin_amdgcn_update_dpp(0, w, 0xB1, 0xF, 0xF, true);
                const int n  = col + 32 * tj;
                uint word; int j;
                if (l & 1) {   // odd lane: row k+1, cols (n-1, n)
                    word = ((uint)nb >> 16) | ((uint)w & 0xFFFF0000u);
                    j = ks * 16 + 8 * hi + 2 * r + 1;
                } else {       // even lane: row k, cols (n, n+1)
                    word = ((uint)w & 0xFFFFu) | ((uint)nb << 16);
                    j = ks * 16 + 8 * hi + 2 * r;
                }
                wsA[((size_t)(rowbase + j) << 5) + (n >> 1)] = word;
            }
    if (l == 0) wsK[bc] = Kc;
}

// ===========================================================================
// Phase 2: per batch, q0 = exp(start+em0 - S0); apply 8 chunk matrices with
// the verified readlane-broadcast matvec; plus the numerator waves.
// ===========================================================================
__global__ __launch_bounds__(64) void crf_apply(
    const float* __restrict__ emissions,
    const int*   __restrict__ tags,
    const int*   __restrict__ mask,
    const float* __restrict__ startT,
    const float* __restrict__ endT,
    const float* __restrict__ trans,
    const uint* __restrict__ wsA,
    const int*  __restrict__ wsK,
    float* __restrict__ out)
{
    const int j = threadIdx.x;

    if (blockIdx.x < B) {
        const int b = blockIdx.x;

        const float e0  = emissions[(size_t)b * NT + j];
        const float sc0 = startT[j] + e0;
        const float S0  = rflf(sc0);
        float q = __expf(sc0 - S0);
        int   K = 0;

#pragma unroll 1
        for (int c = 0; c < NC; ++c) {
            const int bc = b * NC + c;
            // row j of A_c: 32 f16-pair words, fully coalesced
            const int4* ap = (const int4*)(wsA + ((size_t)(bc * 64 + j) << 5));
            union { int4 q4[8]; int w[32]; } A;
#pragma unroll
            for (int m = 0; m < 8; ++m) A.q4[m] = ap[m];
            const int Kc = wsK[bc];

            // pack q pairs (even lane 2n holds (q_2n, q_2n+1))
            const int qi = __float_as_int(q);
            const int qo = __builtin_amdgcn_update_dpp(0, qi, 0xB1, 0xF, 0xF, true);
            const int pk = cvtpk(q, __int_as_float(qo));

            float a0 = 0.f, a1 = 0.f, a2 = 0.f, a3 = 0.f;
            float a4 = 0.f, a5 = 0.f, a6 = 0.f, a7 = 0.f;
#pragma unroll
            for (int n = 0; n < 4; ++n) {
                int u[8];
#pragma unroll
                for (int m = 0; m < 8; ++m)
                    u[m] = __builtin_amdgcn_readlane(pk, 16 * n + 2 * m);
                const int e = 8 * n;
                a0 = dot2(bch2(u[0]), bch2(A.w[e + 0]), a0);
                a1 = dot2(bch2(u[1]), bch2(A.w[e + 1]), a1);
                a2 = dot2(bch2(u[2]), bch2(A.w[e + 2]), a2);
                a3 = dot2(bch2(u[3]), bch2(A.w[e + 3]), a3);
                a4 = dot2(bch2(u[4]), bch2(A.w[e + 4]), a4);
                a5 = dot2(bch2(u[5]), bch2(A.w[e + 5]), a5);
                a6 = dot2(bch2(u[6]), bch2(A.w[e + 6]), a6);
                a7 = dot2(bch2(u[7]), bch2(A.w[e + 7]), a7);
            }
            const float p = ((a0 + a1) + (a2 + a3)) + ((a4 + a5) + (a6 + a7));

            const int bits = __builtin_amdgcn_readfirstlane(__float_as_int(p));
            const int k    = ((bits >> 23) & 255) - 127;
            const float r  = __int_as_float((127 - k) << 23);
            q = p * r;
            K += k + Kc;
        }

        float v = q * __expf(endT[j]);
#pragma unroll
        for (int off = 32; off > 0; off >>= 1)
            v += __shfl_xor(v, off);
        if (j == 0)
            atomicAdd(out, -(S0 + (float)K * 0.69314718f + __logf(v)));

    } else {
        // =============== numerator wave, b = blockIdx.x - B =================
        const int b = blockIdx.x - B;

        float acc = 0.f;
        int   cnt = 0;
#pragma unroll
        for (int m = 0; m < T / 64; ++m) {
            const int t  = j + 64 * m;
            const int mv = mask[t * B + b];
            const int tg = tags[t * B + b];
            cnt += (int)__popcll(__ballot(mv != 0));
            if (t == 0) {
                acc += startT[tg] + emissions[(size_t)b * NT + tg];
            } else if (mv) {
                const int tp = tags[(t - 1) * B + b];
                acc += trans[tp * NT + tg]
                     + emissions[(size_t)(t * B + b) * NT + tg];
            }
        }
#pragma unroll
        for (int off = 32; off > 0; off >>= 1)
            acc += __shfl_xor(acc, off);
        if (j == 0) {
            const int last = tags[(size_t)(cnt - 1) * B + b];
            atomicAdd(out, acc + endT[last]);
        }
    }
}

// ===========================================================================
// Fallback (ws too small): round-3 kernel, verified at ~110 us dispatch.
// ===========================================================================
__global__ __launch_bounds__(64) void crf_fused(
    const float* __restrict__ emissions,
    const int*   __restrict__ tags,
    const int*   __restrict__ mask,
    const float* __restrict__ startT,
    const float* __restrict__ endT,
    const float* __restrict__ trans,
    float* __restrict__ out)
{
    const int j = threadIdx.x;
    __shared__ __align__(16) float ebuf[RING][QS][NT];

    if (blockIdx.x < B) {
        const int b = blockIdx.x;
        h2 Eh[NT / 2];
#pragma unroll
        for (int m = 0; m < NT / 2; ++m) {
            Eh[m].x = (_Float16)__expf(trans[(2 * m)     * NT + j]);
            Eh[m].y = (_Float16)__expf(trans[(2 * m + 1) * NT + j]);
        }
        const int jr = j >> 4;
        const int c0 = (j & 15) * 4;
        float4 sA[4];
        auto issue_q = [&](int g) {
#pragma unroll
            for (int k = 0; k < 4; ++k) {
                const int t = g * QS + 4 * k + jr;
                sA[k] = *(const float4*)&emissions[((size_t)t * B + b) * NT + c0];
            }
        };
        auto write_q = [&](int g) {
#pragma unroll
            for (int k = 0; k < 4; ++k) {
                float4 w;
                w.x = __expf(sA[k].x); w.y = __expf(sA[k].y);
                w.z = __expf(sA[k].z); w.w = __expf(sA[k].w);
                *(float4*)&ebuf[g & (RING - 1)][4 * k + jr][c0] = w;
            }
        };
        for (int g = 0; g < 3; ++g) { issue_q(g); write_q(g); }
        issue_q(3);

        const float e0  = emissions[(size_t)b * NT + j];
        const float sc0 = startT[j] + e0;
        const float S0  = rflf(sc0);
        float q = __expf(sc0 - S0);
        int   K = 0;
        int pk_i;
        {
            const int qi = __float_as_int(q);
            const int qo = __builtin_amdgcn_update_dpp(0, qi, 0xB1, 0xF, 0xF, true);
            pk_i = cvtpk(q, __int_as_float(qo));
        }
        float* eflat = &ebuf[0][0][0];
        int bits_prev;
        int mpre = mask[j * B + b];
        unsigned long long mbc = 0;
        {
            int u[32];
#pragma unroll
            for (int n = 0; n < 32; ++n) u[n] = __builtin_amdgcn_readlane(pk_i, 2 * n);
            float a[8] = {0.f,0.f,0.f,0.f,0.f,0.f,0.f,0.f};
#pragma unroll
            for (int n = 0; n < 32; ++n) a[n & 7] = dot2(bch2(u[n]), Eh[n], a[n & 7]);
            const float p = ((a[0]+a[1])+(a[2]+a[3])) + ((a[4]+a[5])+(a[6]+a[7]));
            bits_prev = __builtin_amdgcn_readfirstlane(__float_as_int(p));
            const int  k = ((bits_prev >> 23) & 255) - 127;
            const float r = __int_as_float((125 - k) << 23);
            const float X1 = eflat[NT + j];
            const int  m1 = mask[B + b];
            if (m1) { q = (p * X1) * r; K = k + 2; }
            const int qo = __builtin_amdgcn_update_dpp(0, __float_as_int(q), 0xB1, 0xF, 0xF, true);
            pk_i = cvtpk(q, __int_as_float(qo));
        }
        float Xc = eflat[2 * NT + j];
        float Xn = eflat[3 * NT + j];
        auto stepF = [&](int s) {
            int u[32];
#pragma unroll
            for (int n = 0; n < 32; ++n) u[n] = __builtin_amdgcn_readlane(pk_i, 2 * n);
            __builtin_amdgcn_sched_barrier(0);
            const int  k = ((bits_prev >> 23) & 255) - 127;
            const float r = __int_as_float((125 - k) << 23);
            K += k + 2;
            float a[8] = {0.f,0.f,0.f,0.f,0.f,0.f,0.f,0.f};
#pragma unroll
            for (int n = 0; n < 32; ++n) a[n & 7] = dot2(bch2(u[n]), Eh[n], a[n & 7]);
            const float sXr = Xc * r;
            const float p = ((a[0]+a[1])+(a[2]+a[3])) + ((a[4]+a[5])+(a[6]+a[7]));
            q = p * sXr;
            bits_prev = __builtin_amdgcn_readfirstlane(__float_as_int(p));
            const int qo = __builtin_amdgcn_update_dpp(0, __float_as_int(q), 0xB1, 0xF, 0xF, true);
            pk_i = cvtpk(q, __int_as_float(qo));
            Xc = Xn;
            Xn = eflat[((s + 2) & 63) * NT + j];
        };
        auto stepM = [&](int s) {
            int u[32];
#pragma unroll
            for (int n = 0; n < 32; ++n) u[n] = __builtin_amdgcn_readlane(pk_i, 2 * n);
            __builtin_amdgcn_sched_barrier(0);
            const int  k = ((bits_prev >> 23) & 255) - 127;
            const float r = __int_as_float((125 - k) << 23);
            const bool mc = (mbc >> (s & 63)) & 1ull;
            const float mf = mc ? 1.0f : 0.0f;
            K += mc ? (k + 2) : 0;
            float a[8] = {0.f,0.f,0.f,0.f,0.f,0.f,0.f,0.f};
#pragma unroll
            for (int n = 0; n < 32; ++n) a[n & 7] = dot2(bch2(u[n]), Eh[n], a[n & 7]);
            const float sXr = Xc * r;
            const float p = ((a[0]+a[1])+(a[2]+a[3])) + ((a[4]+a[5])+(a[6]+a[7]));
            const float qn = p * sXr;
            q = fmaf(mf, qn - q, q);
            bits_prev = __builtin_amdgcn_readfirstlane(__float_as_int(p));
            const int qo = __builtin_amdgcn_update_dpp(0, __float_as_int(q), 0xB1, 0xF, 0xF, true);
            pk_i = cvtpk(q, __int_as_float(qo));
            Xc = Xn;
            Xn = eflat[((s + 2) & 63) * NT + j];
        };
        for (int x = 0; x < NQ; ++x) {
            const int gw = (x + 3 < NQ) ? x + 3 : NQ - 1;
            write_q(gw);
            const int gl = (x + 4 < NQ) ? x + 4 : NQ - 1;
            issue_q(gl);
            if ((x & 3) == 0) {
                mbc = __ballot(mpre != 0);
                const int cn = ((x >> 2) + 1 < 8) ? (x >> 2) + 1 : 7;
                mpre = mask[(cn * 64 + j) * B + b];
            }
            const unsigned qb = (unsigned)(mbc >> ((x & 3) << 4)) & 0xFFFFu;
            const int tt0 = (x == 0) ? 2 : 0;
            if (qb == 0xFFFFu) {
#pragma unroll 1
                for (int tt = tt0; tt < QS; ++tt) stepF(x * QS + tt);
            } else {
#pragma unroll 1
                for (int tt = tt0; tt < QS; ++tt) stepM(x * QS + tt);
            }
        }
        float v = q * __expf(endT[j]);
#pragma unroll
        for (int off = 32; off > 0; off >>= 1) v += __shfl_xor(v, off);
        if (j == 0)
            atomicAdd(out, -(S0 + (float)K * 0.69314718f + __logf(v)));
    } else {
        const int b = blockIdx.x - B;
        float acc = 0.f;
        int   cnt = 0;
#pragma unroll
        for (int m = 0; m < T / 64; ++m) {
            const int t  = j + 64 * m;
            const int mv = mask[t * B + b];
            const int tg = tags[t * B + b];
            cnt += (int)__popcll(__ballot(mv != 0));
            if (t == 0) {
                acc += startT[tg] + emissions[(size_t)b * NT + tg];
            } else if (mv) {
                const int tp = tags[(t - 1) * B + b];
                acc += trans[tp * NT + tg] + emissions[(size_t)(t * B + b) * NT + tg];
            }
        }
#pragma unroll
        for (int off = 32; off > 0; off >>= 1) acc += __shfl_xor(acc, off);
        if (j == 0) {
            const int last = tags[(size_t)(cnt - 1) * B + b];
            atomicAdd(out, acc + endT[last]);
        }
    }
}

extern "C" void kernel_launch(void* const* d_in, const int* in_sizes, int n_in,
                              void* d_out, int out_size, void* d_ws, size_t ws_size,
                              hipStream_t stream) {
    const float* emissions = (const float*)d_in[0];
    const int*   tags      = (const int*)  d_in[1];
    const int*   mask      = (const int*)  d_in[2];
    const float* startT    = (const float*)d_in[3];
    const float* endT      = (const float*)d_in[4];
    const float* trans     = (const float*)d_in[5];
    float* out = (float*)d_out;

    hipMemsetAsync(out, 0, sizeof(float), stream);

    const size_t needA = (size_t)B * NC * 64 * 32 * sizeof(uint);   // 32 MB
    const size_t need  = needA + (size_t)B * NC * sizeof(int);
    if (d_ws != nullptr && ws_size >= need) {
        uint* wsA = (uint*)d_ws;
        int*  wsK = (int*)((char*)d_ws + needA);
        crf_chunks<<<B * NC, 64, 0, stream>>>(emissions, mask, trans, wsA, wsK);
        crf_apply<<<2 * B, 64, 0, stream>>>(emissions, tags, mask, startT, endT,
                                            trans, wsA, wsK, out);
    } else {
        crf_fused<<<2 * B, 64, 0, stream>>>(emissions, tags, mask, startT, endT,
                                            trans, out);
    }
}